// Round 9
// baseline (700.696 us; speedup 1.0000x reference)
//
#include <hip/hip_runtime.h>

// QuatE scoring, MI355X. fp32 via bf16 hi/lo split (3 MFMA products).
// R9: NO-LDS GEMM. Both operands pre-packed as fragment-ordered bf16 hi/lo
// images; each wave streams fragments global->register (A: tile ping-pong,
// B: nb-cluster ping-pong), 12-MFMA clusters, sched_barrier-pinned issue,
// compiler-counted vmcnt, zero barriers. Coalesced LDS-transpose converter.

using bf16x8 = __attribute__((ext_vector_type(8))) short;
using f32x4  = __attribute__((ext_vector_type(4))) float;
using f32x16 = __attribute__((ext_vector_type(16))) float;

#define DEVINL static __device__ __forceinline__

DEVINL void split2(float x0, float x1, unsigned& h, unsigned& l) {
  unsigned u0 = __float_as_uint(x0), u1 = __float_as_uint(x1);
  unsigned h0 = u0 & 0xFFFF0000u, h1 = u1 & 0xFFFF0000u;
  h = (u0 >> 16) | h1;
  float r0 = x0 - __uint_as_float(h0);
  float r1 = x1 - __uint_as_float(h1);
  l = (__float_as_uint(r0) >> 16) | (__float_as_uint(r1) & 0xFFFF0000u);
}

DEVINL void gload16(const void* g, void* l) {
  __builtin_amdgcn_global_load_lds(
      (const __attribute__((address_space(1))) unsigned*)g,
      (__attribute__((address_space(3))) unsigned*)l, 16, 0, 0);
}

// ============================================================================
// Coalesced image converter (32x32x16 fragment order, 256-row image tiles).
// Image tile (256 rows x 32 k) = 32KB: [hi 16KB][lo 16KB]; within plane:
// (row>>5)*2048 + kstep*1024 + khalf*512 + (row&31)*16   (lane-linear).
// Block: 64 rows x one K-tile. Stage to LDS [64][36] f32 (coalesced reads),
// then split + lane-linear 16B writes (coalesced).
// ============================================================================
__global__ void convert_img2(const float* __restrict__ src0,
                             const float* __restrict__ src1, int rows0,
                             int srcK, char* __restrict__ dst, int ktiles)
{
  __shared__ float ld[64][36];
  const int kt = blockIdx.x, rb = blockIdx.y;
  const int t = threadIdx.x;

  {  // stage: thread t reads row rb*64 + (t>>2), 8 floats at k = kt*32 + (t&3)*8
    int r = t >> 2, kc = (t & 3) * 8;
    int row = rb * 64 + r;
    const float* srow = (row < rows0) ? (src0 + (size_t)row * srcK)
                                      : (src1 + (size_t)(row - rows0) * srcK);
    int k0 = kt * 32 + kc;
    float4 v0, v1;
    if (k0 + 8 <= srcK) {
      v0 = *(const float4*)(srow + k0);
      v1 = *(const float4*)(srow + k0 + 4);
    } else {
      float x[8];
#pragma unroll
      for (int j = 0; j < 8; ++j) x[j] = (k0 + j < srcK) ? srow[k0 + j] : 0.f;
      v0 = make_float4(x[0], x[1], x[2], x[3]);
      v1 = make_float4(x[4], x[5], x[6], x[7]);
    }
    *(float4*)&ld[r][kc]     = v0;   // stride 36 floats: 16B-aligned
    *(float4*)&ld[r][kc + 4] = v1;
  }
  __syncthreads();

  {  // split + write: thread t owns image bytes [t*16 .. t*16+16) of each plane
    int g = t >> 7, s = (t >> 6) & 1, kh = (t >> 5) & 1, r31 = t & 31;
    int row = g * 32 + r31;
    int k = s * 16 + kh * 8;
    float x[8];
#pragma unroll
    for (int j = 0; j < 8; ++j) x[j] = ld[row][k + j];
    unsigned hh[4], llv[4];
    split2(x[0], x[1], hh[0], llv[0]);
    split2(x[2], x[3], hh[1], llv[1]);
    split2(x[4], x[5], hh[2], llv[2]);
    split2(x[6], x[7], hh[3], llv[3]);
    int tile_rt = rb >> 2;                 // 256-row image tile
    int gbase = (rb & 3) * 2;              // group base within tile
    char* base = dst + ((size_t)tile_rt * ktiles + kt) * 32768
               + (gbase + g) * 2048 + s * 1024 + kh * 512 + r31 * 16;
    *(uint4*)base           = make_uint4(hh[0], hh[1], hh[2], hh[3]);
    *(uint4*)(base + 16384) = make_uint4(llv[0], llv[1], llv[2], llv[3]);
  }
}

// ============================================================================
// No-LDS direct-stream GEMM: 256x256 tile, 8 waves 4x2 (wave tile 64x128),
// BK=32, 32x32x16 MFMA. A: 8 b128/wave/tile (tile ping-pong, 1-tile
// prefetch). B: 4 b128 per nb-cluster (ping-pong, 1-cluster prefetch).
// No shared memory, no barriers -- waves free-run, compiler-counted vmcnt.
// ============================================================================
__global__ __launch_bounds__(512, 2) void gemm_dir(
    const char* __restrict__ Aimg, const char* __restrict__ Bimg, int ktiles,
    float* __restrict__ C, int MT, int NT, int KS, int swz)
{
  const int bid = blockIdx.x;

  int mt, nt, ks;
  if (swz) {  // grid 256: 4 nt-blocks of one (mt,ks) on the same XCD
    int x = bid & 7, w = bid >> 3;
    nt = w & 3;
    int g = x + (w >> 2) * 8;
    mt = g & 15; ks = g >> 4;
  } else {
    nt = bid % NT; int q = bid / NT; mt = q % MT; ks = q / MT;
  }

  const int kt0 = (ktiles * ks) / KS;
  const int kt1 = (ktiles * (ks + 1)) / KS;

  const char* Akt = Aimg + ((size_t)mt * ktiles + kt0) * 32768;
  const char* Bkt = Bimg + ((size_t)nt * ktiles + kt0) * 32768;

  const int wid = threadIdx.x >> 6, lane = threadIdx.x & 63;
  const int wr = wid >> 1, wc = wid & 1;       // 4 row-waves x 2 col-waves

  const int aoff = wr * 2 * 2048 + lane * 16;  // + mb*2048 + s*1024 + pl*16384
  const int boff = wc * 4 * 2048 + lane * 16;  // + nb*2048 + s*1024 + pl*16384

  f32x16 acc[2][4];
#pragma unroll
  for (int mb = 0; mb < 2; ++mb)
#pragma unroll
    for (int nb = 0; nb < 4; ++nb)
#pragma unroll
      for (int e = 0; e < 16; ++e) acc[mb][nb][e] = 0.f;

  bf16x8 aA[8], aB[8];   // [mb*4 + s*2 + pl], tile ping-pong
  bf16x8 bb[2][4];       // [parity][s*2 + pl], nb ping-pong

#define LDA(DST, BASE)                                                         \
  {                                                                            \
    _Pragma("unroll")                                                          \
    for (int mb = 0; mb < 2; ++mb)                                             \
      _Pragma("unroll")                                                        \
      for (int s = 0; s < 2; ++s)                                              \
        _Pragma("unroll")                                                      \
        for (int pl = 0; pl < 2; ++pl)                                         \
          (DST)[mb * 4 + s * 2 + pl] = *(const bf16x8*)((BASE) +               \
              pl * 16384 + mb * 2048 + s * 1024 + aoff);                       \
  }
#define LDB(PAR, BASE, NB)                                                     \
  {                                                                            \
    _Pragma("unroll")                                                          \
    for (int s = 0; s < 2; ++s)                                                \
      _Pragma("unroll")                                                        \
      for (int pl = 0; pl < 2; ++pl)                                           \
        bb[PAR][s * 2 + pl] = *(const bf16x8*)((BASE) +                        \
            pl * 16384 + (NB) * 2048 + s * 1024 + boff);                       \
  }
#define SB() __builtin_amdgcn_sched_barrier(0)
#define CL(AC, PAR, NB)                                                        \
  {                                                                            \
    __builtin_amdgcn_s_setprio(1);                                             \
    _Pragma("unroll")                                                          \
    for (int mb = 0; mb < 2; ++mb)                                             \
      _Pragma("unroll")                                                        \
      for (int s = 0; s < 2; ++s) {                                            \
        f32x16* a = &acc[mb][NB];                                              \
        bf16x8 ah = (AC)[mb * 4 + s * 2 + 0];                                  \
        bf16x8 al = (AC)[mb * 4 + s * 2 + 1];                                  \
        bf16x8 bh = bb[PAR][s * 2 + 0];                                        \
        bf16x8 bl = bb[PAR][s * 2 + 1];                                        \
        *a = __builtin_amdgcn_mfma_f32_32x32x16_bf16(ah, bh, *a, 0, 0, 0);     \
        *a = __builtin_amdgcn_mfma_f32_32x32x16_bf16(al, bh, *a, 0, 0, 0);     \
        *a = __builtin_amdgcn_mfma_f32_32x32x16_bf16(ah, bl, *a, 0, 0, 0);     \
      }                                                                        \
    __builtin_amdgcn_s_setprio(0);                                             \
  }
#define TILE(AC, AN, NX)                                                       \
  {                                                                            \
    LDB(1, Bkt, 1);                        SB(); CL(AC, 0, 0); SB();           \
    LDB(0, Bkt, 2);                        SB(); CL(AC, 1, 1); SB();           \
    LDB(1, Bkt, 3);                                                            \
    if (NX) LDA(AN, Akt + 32768);          SB(); CL(AC, 0, 2); SB();           \
    if (NX) LDB(0, Bkt + 32768, 0);        SB(); CL(AC, 1, 3); SB();           \
    Akt += 32768; Bkt += 32768;                                                \
  }

  // prologue: A(kt0) + B(kt0, nb=0)
  LDA(aA, Akt);
  LDB(0, Bkt, 0);
  SB();

  int kt = kt0;
  for (; kt + 2 <= kt1; kt += 2) {
    TILE(aA, aB, true);
    TILE(aB, aA, (kt + 2) < kt1);
  }
  if (kt < kt1) TILE(aA, aB, false);
#undef LDA
#undef LDB
#undef SB
#undef CL
#undef TILE

  // C write. 32x32 D layout: col = lane&31, row = (reg&3) + 8*(reg>>2) + 4*(lane>>5)
  float* Cb = C + (size_t)ks * (size_t)(MT * 256) * 1024;
  const long rowbase = (long)mt * 256 + wr * 64 + 4 * (lane >> 5);
  const long colbase = (long)nt * 256 + wc * 128 + (lane & 31);
#pragma unroll
  for (int mb = 0; mb < 2; ++mb)
#pragma unroll
    for (int nb = 0; nb < 4; ++nb)
#pragma unroll
      for (int reg = 0; reg < 16; ++reg) {
        long row = rowbase + mb * 32 + (reg & 3) + 8 * (reg >> 2);
        long col = colbase + nb * 32;
        Cb[(size_t)row * 1024 + col] = acc[mb][nb][reg];
      }
}

// ============================================================================
// R3 fallback path (used only if ws too small for A-images)
// ============================================================================
__global__ void convert_b16(const float* __restrict__ src, int srcK,
                            char* __restrict__ dst)
{
  const int tile = blockIdx.x;
  const int wrow = threadIdx.x;
  char* base = dst + (size_t)tile * 32768;
  const float* srow = src + (size_t)wrow * srcK;
#pragma unroll
  for (int kc8 = 0; kc8 < 4; ++kc8) {
    int k0 = tile * 32 + kc8 * 8;
    float x[8];
    if (k0 + 8 <= srcK) {
      float4 v0 = *(const float4*)(srow + k0);
      float4 v1 = *(const float4*)(srow + k0 + 4);
      x[0] = v0.x; x[1] = v0.y; x[2] = v0.z; x[3] = v0.w;
      x[4] = v1.x; x[5] = v1.y; x[6] = v1.z; x[7] = v1.w;
    } else {
#pragma unroll
      for (int j = 0; j < 8; ++j) x[j] = (k0 + j < srcK) ? srow[k0 + j] : 0.f;
    }
    unsigned hh[4], ll[4];
    split2(x[0], x[1], hh[0], ll[0]);
    split2(x[2], x[3], hh[1], ll[1]);
    split2(x[4], x[5], hh[2], ll[2]);
    split2(x[6], x[7], hh[3], ll[3]);
    int lchunk = (wrow & 15) + kc8 * 16;
    int n16 = wrow >> 4;
    *(uint4*)(base + (size_t)n16 * 1024 + lchunk * 16)         = make_uint4(hh[0], hh[1], hh[2], hh[3]);
    *(uint4*)(base + 16384 + (size_t)n16 * 1024 + lchunk * 16) = make_uint4(ll[0], ll[1], ll[2], ll[3]);
  }
}

__global__ void pad_r(const float* __restrict__ src, float* __restrict__ dst)
{
  int row = blockIdx.y;
  int k = threadIdx.x * 4;
  float4 v = make_float4(0.f, 0.f, 0.f, 0.f);
  if (k + 3 < 500) v = *(const float4*)(src + (size_t)row * 500 + k);
  *(float4*)(dst + (size_t)row * 512 + k) = v;
}

__global__ __launch_bounds__(512, 2) void gemm3p(
    const float* __restrict__ A0, const float* __restrict__ A1, int mtA0, long lda,
    const char* __restrict__ Bimg, int ktilesTot,
    float* __restrict__ C, long ldc, int MT, int NT, int KS, int swz)
{
  extern __shared__ char smemd[];
  const int tid = threadIdx.x;
  const int bid = blockIdx.x;

  int mt, nt, ks;
  if (swz) {
    int x = bid & 7, w = bid >> 3;
    nt = w & 3;
    int g = x + (w >> 2) * 8;
    mt = g & 15; ks = g >> 4;
  } else {
    nt = bid % NT; int q = bid / NT; mt = q % MT; ks = q / MT;
  }

  const int kt0 = (ktilesTot * ks) / KS;
  const int kt1 = (ktilesTot * (ks + 1)) / KS;

  const float* Ablk = (mt < mtA0) ? (A0 + (size_t)mt * 256 * lda)
                                  : (A1 + (size_t)(mt - mtA0) * 256 * lda);
  const char* Bt = Bimg + ((size_t)nt * ktilesTot + kt0) * 32768;

  const int wid = tid >> 6, lane = tid & 63;
  const int wr = wid >> 2, wc = wid & 3;
  const int l15 = lane & 15, lq = lane >> 4;

  const float* aSrc = Ablk + (size_t)(wid * 32 + (lane >> 3)) * lda
                      + (size_t)kt0 * 32 + 4 * (lane & 7);

  int awoff[4];
  {
    int kg = (lane & 7) >> 1, half = lane & 1;
#pragma unroll
    for (int i = 0; i < 4; ++i) {
      int m15 = (lane >> 3) + 8 * (i & 1);
      awoff[i] = (2 * wid + (i >> 1)) * 2048 + (((m15 ^ kg) + kg * 16) << 4) + half * 8;
    }
  }
  const int aroff = (((l15 ^ lq) + lq * 16) << 4);
  const int bbase = 32768 + (wc * 4) * 1024 + lane * 16;

  f32x4 acc[8][4];
#pragma unroll
  for (int m = 0; m < 8; ++m)
#pragma unroll
    for (int j = 0; j < 4; ++j)
#pragma unroll
      for (int e = 0; e < 4; ++e) acc[m][j][e] = 0.f;

  float4 aR[4];

#define ISSUE_A(KT)                                                            \
  {                                                                            \
    const float* p_ = aSrc + (size_t)((KT) - kt0) * 32;                        \
    _Pragma("unroll")                                                          \
    for (int i = 0; i < 4; ++i) aR[i] = *(const float4*)(p_ + (size_t)(8 * i) * lda); \
  }
#define ISSUE_B(DST, KT)                                                       \
  {                                                                            \
    const char* p_ = Bt + (size_t)((KT) - kt0) * 32768 + wid * 4096 + lane * 16; \
    _Pragma("unroll")                                                          \
    for (int i = 0; i < 4; ++i)                                                \
      gload16(p_ + i * 1024, (DST) + 32768 + wid * 4096 + i * 1024);           \
  }
#define WRITE_A(DST)                                                           \
  {                                                                            \
    _Pragma("unroll")                                                          \
    for (int i = 0; i < 4; ++i) {                                              \
      unsigned h0_, l0_, h1_, l1_;                                             \
      split2(aR[i].x, aR[i].y, h0_, l0_);                                      \
      split2(aR[i].z, aR[i].w, h1_, l1_);                                      \
      *(uint2*)((DST) + awoff[i])        = make_uint2(h0_, h1_);               \
      *(uint2*)((DST) + awoff[i] + 1024) = make_uint2(l0_, l1_);               \
    }                                                                          \
  }

  ISSUE_A(kt0);
  ISSUE_B(smemd, kt0);
  WRITE_A(smemd);
  asm volatile("s_waitcnt vmcnt(0)" ::: "memory");
  asm volatile("s_waitcnt lgkmcnt(0)" ::: "memory");
  __builtin_amdgcn_s_barrier();

  for (int kt = kt0; kt < kt1; ++kt) {
    char* bufc = smemd + (size_t)((kt - kt0) & 1) * 65536;
    char* bufn = smemd + (size_t)(((kt - kt0) & 1) ^ 1) * 65536;
    const bool nx = (kt + 1 < kt1);

    if (nx) { ISSUE_A(kt + 1); ISSUE_B(bufn, kt + 1); }

    bf16x8 bh[4], bl[4];
#pragma unroll
    for (int j = 0; j < 4; ++j) {
      bh[j] = *(const bf16x8*)(bufc + bbase + j * 1024);
      bl[j] = *(const bf16x8*)(bufc + bbase + j * 1024 + 16384);
    }

    __builtin_amdgcn_s_setprio(1);
#pragma unroll
    for (int m = 0; m < 4; ++m) {
      const char* ab = bufc + (wr * 8 + m) * 2048;
      bf16x8 ah = *(const bf16x8*)(ab + aroff);
      bf16x8 al = *(const bf16x8*)(ab + aroff + 1024);
#pragma unroll
      for (int j = 0; j < 4; ++j) {
        acc[m][j] = __builtin_amdgcn_mfma_f32_16x16x32_bf16(ah, bh[j], acc[m][j], 0, 0, 0);
        acc[m][j] = __builtin_amdgcn_mfma_f32_16x16x32_bf16(al, bh[j], acc[m][j], 0, 0, 0);
        acc[m][j] = __builtin_amdgcn_mfma_f32_16x16x32_bf16(ah, bl[j], acc[m][j], 0, 0, 0);
      }
    }
    __builtin_amdgcn_s_setprio(0);

    __builtin_amdgcn_sched_barrier(0);
    if (nx) WRITE_A(bufn);

    __builtin_amdgcn_s_setprio(1);
#pragma unroll
    for (int m = 4; m < 8; ++m) {
      const char* ab = bufc + (wr * 8 + m) * 2048;
      bf16x8 ah = *(const bf16x8*)(ab + aroff);
      bf16x8 al = *(const bf16x8*)(ab + aroff + 1024);
#pragma unroll
      for (int j = 0; j < 4; ++j) {
        acc[m][j] = __builtin_amdgcn_mfma_f32_16x16x32_bf16(ah, bh[j], acc[m][j], 0, 0, 0);
        acc[m][j] = __builtin_amdgcn_mfma_f32_16x16x32_bf16(al, bh[j], acc[m][j], 0, 0, 0);
        acc[m][j] = __builtin_amdgcn_mfma_f32_16x16x32_bf16(ah, bl[j], acc[m][j], 0, 0, 0);
      }
    }
    __builtin_amdgcn_s_setprio(0);

    asm volatile("s_waitcnt vmcnt(0)" ::: "memory");
    asm volatile("s_waitcnt lgkmcnt(0)" ::: "memory");
    __builtin_amdgcn_s_barrier();
  }
#undef ISSUE_A
#undef ISSUE_B
#undef WRITE_A

  float* Cb = C + (size_t)ks * (size_t)(MT * 256) * (size_t)ldc;
  const long rowbase = (long)mt * 256 + wr * 128 + lq * 4;
  const long colbase = (long)nt * 256 + wc * 64 + l15;
#pragma unroll
  for (int m = 0; m < 8; ++m)
#pragma unroll
    for (int j = 0; j < 4; ++j)
#pragma unroll
      for (int reg = 0; reg < 4; ++reg) {
        long row = rowbase + m * 16 + reg;
        long col = colbase + j * 16;
        Cb[(size_t)row * ldc + col] = acc[m][j][reg];
      }
}

// ---------------- epilogue: k-split sum, norm, Hamilton, row dot, sigmoid ----
__global__ void epilogue_kernel(const float* __restrict__ C1, const float* __restrict__ C2,
                                float* __restrict__ out, int KS)
{
  const int b = blockIdx.x;
  const int d = threadIdx.x;
  const size_t SZ = 4096ull * 1024ull;

  float Hq[4], Tq[4], Rq[4];
#pragma unroll
  for (int q = 0; q < 4; ++q) {
    float hv = 0.f, tv = 0.f;
    for (int ks = 0; ks < KS; ++ks) {
      hv += C1[ks * SZ + (size_t)b * 1024 + q * 256 + d];
      tv += C1[ks * SZ + (size_t)(b + 2048) * 1024 + q * 256 + d];
    }
    Hq[q] = hv; Tq[q] = tv;
    Rq[q] = C2[(size_t)b * 1024 + q * 256 + d];
  }
  float nn = Rq[0]*Rq[0] + Rq[1]*Rq[1] + Rq[2]*Rq[2] + Rq[3]*Rq[3];
  float Qr = Hq[0]*Rq[0] - Hq[1]*Rq[1] - Hq[2]*Rq[2] - Hq[3]*Rq[3];
  float Qi = Hq[0]*Rq[1] + Hq[1]*Rq[0] + Hq[2]*Rq[3] - Hq[3]*Rq[2];
  float Qj = Hq[0]*Rq[2] - Hq[1]*Rq[3] + Hq[2]*Rq[0] + Hq[3]*Rq[1];
  float Qk = Hq[0]*Rq[3] + Hq[1]*Rq[2] - Hq[2]*Rq[1] + Hq[3]*Rq[0];
  float ss = Qr*Tq[0] + Qi*Tq[1] + Qj*Tq[2] + Qk*Tq[3];

#pragma unroll
  for (int o = 32; o; o >>= 1) {
    ss += __shfl_xor(ss, o);
    nn += __shfl_xor(nn, o);
  }
  __shared__ float red[8];
  int lane = d & 63, w = d >> 6;
  if (lane == 0) { red[w] = ss; red[4 + w] = nn; }
  __syncthreads();
  if (d == 0) {
    float S = red[0] + red[1] + red[2] + red[3];
    float N = red[4] + red[5] + red[6] + red[7];
    float score = sqrtf(N) * S;
    out[b] = 1.f / (1.f + expf(-score));
  }
}

// ---------------- launch ----------------
extern "C" void kernel_launch(void* const* d_in, const int* in_sizes, int n_in,
                              void* d_out, int out_size, void* d_ws, size_t ws_size,
                              hipStream_t stream)
{
  const float* h = (const float*)d_in[0];
  const float* t = (const float*)d_in[1];
  const float* r = (const float*)d_in[2];
  const float* We[4] = {(const float*)d_in[3], (const float*)d_in[4],
                        (const float*)d_in[5], (const float*)d_in[6]};
  const float* Wr[4] = {(const float*)d_in[7], (const float*)d_in[8],
                        (const float*)d_in[9], (const float*)d_in[10]};
  float* out = (float*)d_out;
  char* ws = (char*)d_ws;

  // ---- image path ws layout ----
  const size_t offA  = 0;                               // A: 16 rt *625 kt *32KB = 327,680,000
  const size_t offB  = 327680000;                       // B: 4 *625 *32KB = 81,920,000
  const size_t offWr = offB + 81920000;                 // Wr: 4 *16 *32KB
  const size_t offRi = offWr + 2097152;                 // r:  8 rt *16 kt *32KB
  const size_t offC1 = offRi + 4194304;
  const size_t C1sz  = 4096ull * 1024ull * 4ull;        // 16,777,216 per ks
  const size_t offC2 = offC1 + 4 * C1sz;
  const size_t needImg = offC2 + 8388608;               // ~491 MB

  if (ws_size >= needImg) {
    float* C1 = (float*)(ws + offC1);
    float* C2 = (float*)(ws + offC2);

    // A images: rows 0..2047 = h, 2048..4095 = t   (4096 rows = 64 x 64-row blocks)
    convert_img2<<<dim3(625, 64), 256, 0, stream>>>(h, t, 2048, 20000, ws + offA, 625);
    for (int q = 0; q < 4; ++q) {
      convert_img2<<<dim3(625, 4), 256, 0, stream>>>(
          We[q], We[q], 2048, 20000, ws + offB + (size_t)q * 625 * 32768, 625);
      convert_img2<<<dim3(16, 4), 256, 0, stream>>>(
          Wr[q], Wr[q], 2048, 500, ws + offWr + (size_t)q * 16 * 32768, 16);
    }
    convert_img2<<<dim3(16, 32), 256, 0, stream>>>(r, r, 2048, 500, ws + offRi, 16);

    // main: M=4096 (16 mt), N=1024 (4 nt), K=20000 (625 kt), KS=4 -> 256 blocks
    gemm_dir<<<dim3(256), 512, 0, stream>>>(
        ws + offA, ws + offB, 625, C1, 16, 4, 4, 1);
    // r: M=2048 (8 mt), N=1024, K=512 (16 kt), KS=1 -> 32 blocks
    gemm_dir<<<dim3(32), 512, 0, stream>>>(
        ws + offRi, ws + offWr, 16, C2, 8, 4, 1, 0);

    epilogue_kernel<<<dim3(2048), 256, 0, stream>>>(C1, C2, out, 4);
    return;
  }

  // ---- fallback: R3 path ----
  const size_t fB  = 0;
  const size_t fWr = 81920000;
  const size_t fR  = fWr + 2097152;
  const size_t fC1 = fR + 4194304;
  const int KS = (ws_size >= fC1 + 4 * C1sz + 8388608ull) ? 4 : 2;
  const size_t fC2 = fC1 + (size_t)KS * C1sz;

  float* rpad = (float*)(ws + fR);
  float* C1   = (float*)(ws + fC1);
  float* C2   = (float*)(ws + fC2);

  for (int q = 0; q < 4; ++q) {
    convert_b16<<<dim3(625), 256, 0, stream>>>(We[q], 20000, ws + fB + (size_t)q * 625 * 32768);
    convert_b16<<<dim3(16), 256, 0, stream>>>(Wr[q], 500, ws + fWr + (size_t)q * 16 * 32768);
  }
  pad_r<<<dim3(1, 2048), 128, 0, stream>>>(r, rpad);

  gemm3p<<<dim3(16 * 4 * KS), 512, 131072, stream>>>(
      h, t, 8, 20000L, (const char*)(ws + fB), 625,
      C1, 1024L, 16, 4, KS, KS == 4 ? 1 : 0);
  gemm3p<<<dim3(32), 512, 131072, stream>>>(
      rpad, rpad, 8, 512L, (const char*)(ws + fWr), 16,
      C2, 1024L, 8, 4, 1, 0);

  epilogue_kernel<<<dim3(2048), 256, 0, stream>>>(C1, C2, out, KS);
}

// Round 10
// 616.141 us; speedup vs baseline: 1.1372x; 1.1372x over previous
//
#include <hip/hip_runtime.h>

// QuatE scoring, MI355X. fp32 via bf16 hi/lo split (3 MFMA products).
// R10: 128x128 tile, 4 waves (2x2), 2 blocks/CU (independent barrier domains),
// dbuf 2x32KB LDS, both operands image-packed (128-row tiles), gload_lds
// staging, distance-4 MFMA ordering, coalesced LDS-transpose converters.

using bf16x8 = __attribute__((ext_vector_type(8))) short;
using f32x4  = __attribute__((ext_vector_type(4))) float;
using f32x16 = __attribute__((ext_vector_type(16))) float;

#define DEVINL static __device__ __forceinline__

DEVINL void split2(float x0, float x1, unsigned& h, unsigned& l) {
  unsigned u0 = __float_as_uint(x0), u1 = __float_as_uint(x1);
  unsigned h0 = u0 & 0xFFFF0000u, h1 = u1 & 0xFFFF0000u;
  h = (u0 >> 16) | h1;
  float r0 = x0 - __uint_as_float(h0);
  float r1 = x1 - __uint_as_float(h1);
  l = (__float_as_uint(r0) >> 16) | (__float_as_uint(r1) & 0xFFFF0000u);
}

DEVINL void gload16(const void* g, void* l) {
  __builtin_amdgcn_global_load_lds(
      (const __attribute__((address_space(1))) unsigned*)g,
      (__attribute__((address_space(3))) unsigned*)l, 16, 0, 0);
}

// ============================================================================
// Coalesced image converter, 128-row image tiles (32x32x16 fragment order).
// Image tile (128 rows x 32 k) = 16KB: [hi 8KB][lo 8KB]; within plane:
// (row>>5)*2048 + kstep*1024 + khalf*512 + (row&31)*16   (lane-linear).
// Block: 64 rows x 1 K-tile; stage to LDS [64][36] (coalesced 128B reads),
// split + lane-linear 16B writes.
// ============================================================================
__global__ void convert_img128(const float* __restrict__ src0,
                               const float* __restrict__ src1, int rows0,
                               int srcK, char* __restrict__ dst, int ktiles)
{
  __shared__ float ld[64][36];
  const int kt = blockIdx.x, rb = blockIdx.y;
  const int t = threadIdx.x;

  {  // stage: thread t reads row rb*64 + (t>>2), 8 floats at k = kt*32 + (t&3)*8
    int r = t >> 2, kc = (t & 3) * 8;
    int row = rb * 64 + r;
    const float* srow = (row < rows0) ? (src0 + (size_t)row * srcK)
                                      : (src1 + (size_t)(row - rows0) * srcK);
    int k0 = kt * 32 + kc;
    float4 v0, v1;
    if (k0 + 8 <= srcK) {
      v0 = *(const float4*)(srow + k0);
      v1 = *(const float4*)(srow + k0 + 4);
    } else {
      float x[8];
#pragma unroll
      for (int j = 0; j < 8; ++j) x[j] = (k0 + j < srcK) ? srow[k0 + j] : 0.f;
      v0 = make_float4(x[0], x[1], x[2], x[3]);
      v1 = make_float4(x[4], x[5], x[6], x[7]);
    }
    *(float4*)&ld[r][kc]     = v0;
    *(float4*)&ld[r][kc + 4] = v1;
  }
  __syncthreads();

  {  // split + write: thread t owns one 16B chunk of each plane
    int g = t >> 7, s = (t >> 6) & 1, kh = (t >> 5) & 1, r31 = t & 31;
    int row = g * 32 + r31;
    int k = s * 16 + kh * 8;
    float x[8];
#pragma unroll
    for (int j = 0; j < 8; ++j) x[j] = ld[row][k + j];
    unsigned hh[4], llv[4];
    split2(x[0], x[1], hh[0], llv[0]);
    split2(x[2], x[3], hh[1], llv[1]);
    split2(x[4], x[5], hh[2], llv[2]);
    split2(x[6], x[7], hh[3], llv[3]);
    int tile_rt = rb >> 1;                // 128-row image tile index
    int gbase = (rb & 1) * 2;             // group base within tile
    char* base = dst + ((size_t)tile_rt * ktiles + kt) * 16384
               + (gbase + g) * 2048 + s * 1024 + kh * 512 + r31 * 16;
    *(uint4*)base          = make_uint4(hh[0], hh[1], hh[2], hh[3]);
    *(uint4*)(base + 8192) = make_uint4(llv[0], llv[1], llv[2], llv[3]);
  }
}

// ============================================================================
// 128x128-tile GEMM: 4 waves (2x2, wave tile 64x64), BK=32, 32x32x16 MFMA.
// LDS dbuf 2 x (A 16KB + B 16KB) = 64KB -> 2 blocks/CU (independent barrier
// domains). Per K-tile: {stage t+1 async; 16 frag ds_reads; 24 MFMAs in
// distance-4 order; vmcnt(0)(loads issued a full tile earlier); barrier}.
// ============================================================================
__global__ __launch_bounds__(256, 2) void gemm_t128(
    const char* __restrict__ Aimg, const char* __restrict__ Bimg, int ktiles,
    float* __restrict__ C, int MT, int NT, int KS, int swz)
{
  __shared__ __align__(16) char smem[65536];
  const int bid = blockIdx.x;

  int mt, nt, ks;
  if (swz) {  // grid 512: XCD x hosts pairs P in [8x,8x+8); all 64 co-resident
    int x = bid & 7, i = bid >> 3;
    nt = i & 7;
    int P = x * 8 + (i >> 3);
    ks = P & 1; mt = P >> 1;
  } else {
    nt = bid % NT; int q = bid / NT; mt = q % MT; ks = q / MT;
  }

  const int kt0 = (ktiles * ks) / KS;
  const int kt1 = (ktiles * (ks + 1)) / KS;

  const char* Ab = Aimg + ((size_t)mt * ktiles + kt0) * 16384;
  const char* Bb = Bimg + ((size_t)nt * ktiles + kt0) * 16384;

  const int wid = threadIdx.x >> 6, lane = threadIdx.x & 63;
  const int wr = wid >> 1, wc = wid & 1;      // 2x2 wave grid, 64x64 per wave

  f32x16 acc[2][2];
#pragma unroll
  for (int mb = 0; mb < 2; ++mb)
#pragma unroll
    for (int nb = 0; nb < 2; ++nb)
#pragma unroll
      for (int e = 0; e < 16; ++e) acc[mb][nb][e] = 0.f;

  // prologue: stage kt0 into buf0
  {
    const char* As = Ab + wid * 4096 + lane * 16;
    const char* Bs = Bb + wid * 4096 + lane * 16;
#pragma unroll
    for (int i = 0; i < 4; ++i) gload16(As + i * 1024, smem + wid * 4096 + i * 1024);
#pragma unroll
    for (int i = 0; i < 4; ++i) gload16(Bs + i * 1024, smem + 16384 + wid * 4096 + i * 1024);
  }
  asm volatile("s_waitcnt vmcnt(0)" ::: "memory");
  __builtin_amdgcn_s_barrier();

  for (int kt = kt0; kt < kt1; ++kt) {
    char* bufc = smem + (size_t)((kt - kt0) & 1) * 32768;
    char* bufn = smem + (size_t)(((kt - kt0) & 1) ^ 1) * 32768;
    const bool nx = (kt + 1 < kt1);

    if (nx) {  // async stage of next K-tile; drained at end of THIS tile
      const char* As = Ab + (size_t)(kt + 1 - kt0) * 16384 + wid * 4096 + lane * 16;
      const char* Bs = Bb + (size_t)(kt + 1 - kt0) * 16384 + wid * 4096 + lane * 16;
#pragma unroll
      for (int i = 0; i < 4; ++i) gload16(As + i * 1024, bufn + wid * 4096 + i * 1024);
#pragma unroll
      for (int i = 0; i < 4; ++i) gload16(Bs + i * 1024, bufn + 16384 + wid * 4096 + i * 1024);
    }

    // fragment reads: 8 A + 8 B ds_read_b128, conflict-free, minimal dup
    bf16x8 ah[2][2], al[2][2], bh[2][2], bl[2][2];   // [mb|nb][s]
#pragma unroll
    for (int mb = 0; mb < 2; ++mb)
#pragma unroll
      for (int s = 0; s < 2; ++s) {
        const char* p = bufc + (wr * 2 + mb) * 2048 + s * 1024 + lane * 16;
        ah[mb][s] = *(const bf16x8*)p;
        al[mb][s] = *(const bf16x8*)(p + 8192);
      }
#pragma unroll
    for (int nb = 0; nb < 2; ++nb)
#pragma unroll
      for (int s = 0; s < 2; ++s) {
        const char* p = bufc + 16384 + (wc * 2 + nb) * 2048 + s * 1024 + lane * 16;
        bh[nb][s] = *(const bf16x8*)p;
        bl[nb][s] = *(const bf16x8*)(p + 8192);
      }

    // 24 MFMAs, accumulator reuse distance = 4 (p,s outer; mb,nb inner)
    __builtin_amdgcn_s_setprio(1);
#pragma unroll
    for (int p = 0; p < 3; ++p)
#pragma unroll
      for (int s = 0; s < 2; ++s)
#pragma unroll
        for (int mb = 0; mb < 2; ++mb)
#pragma unroll
          for (int nb = 0; nb < 2; ++nb) {
            bf16x8 av = (p == 1) ? al[mb][s] : ah[mb][s];
            bf16x8 bv = (p == 2) ? bl[nb][s] : bh[nb][s];
            acc[mb][nb] = __builtin_amdgcn_mfma_f32_32x32x16_bf16(av, bv, acc[mb][nb], 0, 0, 0);
          }
    __builtin_amdgcn_s_setprio(0);

    asm volatile("s_waitcnt vmcnt(0)" ::: "memory");  // stage issued a full tile ago
    __builtin_amdgcn_s_barrier();
  }

  // C write. 32x32 D layout: col = lane&31, row = (reg&3) + 8*(reg>>2) + 4*(lane>>5)
  float* Cb = C + (size_t)ks * (size_t)(MT * 128) * 1024;
  const long rowbase = (long)mt * 128 + wr * 64 + 4 * (lane >> 5);
  const long colbase = (long)nt * 128 + wc * 64 + (lane & 31);
#pragma unroll
  for (int mb = 0; mb < 2; ++mb)
#pragma unroll
    for (int nb = 0; nb < 2; ++nb)
#pragma unroll
      for (int reg = 0; reg < 16; ++reg) {
        long row = rowbase + mb * 32 + (reg & 3) + 8 * (reg >> 2);
        long col = colbase + nb * 32;
        Cb[(size_t)row * 1024 + col] = acc[mb][nb][reg];
      }
}

// ============================================================================
// R3 fallback path (used only if ws too small for A-images)
// ============================================================================
__global__ void convert_b16(const float* __restrict__ src, int srcK,
                            char* __restrict__ dst)
{
  const int tile = blockIdx.x;
  const int wrow = threadIdx.x;
  char* base = dst + (size_t)tile * 32768;
  const float* srow = src + (size_t)wrow * srcK;
#pragma unroll
  for (int kc8 = 0; kc8 < 4; ++kc8) {
    int k0 = tile * 32 + kc8 * 8;
    float x[8];
    if (k0 + 8 <= srcK) {
      float4 v0 = *(const float4*)(srow + k0);
      float4 v1 = *(const float4*)(srow + k0 + 4);
      x[0] = v0.x; x[1] = v0.y; x[2] = v0.z; x[3] = v0.w;
      x[4] = v1.x; x[5] = v1.y; x[6] = v1.z; x[7] = v1.w;
    } else {
#pragma unroll
      for (int j = 0; j < 8; ++j) x[j] = (k0 + j < srcK) ? srow[k0 + j] : 0.f;
    }
    unsigned hh[4], ll[4];
    split2(x[0], x[1], hh[0], ll[0]);
    split2(x[2], x[3], hh[1], ll[1]);
    split2(x[4], x[5], hh[2], ll[2]);
    split2(x[6], x[7], hh[3], ll[3]);
    int lchunk = (wrow & 15) + kc8 * 16;
    int n16 = wrow >> 4;
    *(uint4*)(base + (size_t)n16 * 1024 + lchunk * 16)         = make_uint4(hh[0], hh[1], hh[2], hh[3]);
    *(uint4*)(base + 16384 + (size_t)n16 * 1024 + lchunk * 16) = make_uint4(ll[0], ll[1], ll[2], ll[3]);
  }
}

__global__ void pad_r(const float* __restrict__ src, float* __restrict__ dst)
{
  int row = blockIdx.y;
  int k = threadIdx.x * 4;
  float4 v = make_float4(0.f, 0.f, 0.f, 0.f);
  if (k + 3 < 500) v = *(const float4*)(src + (size_t)row * 500 + k);
  *(float4*)(dst + (size_t)row * 512 + k) = v;
}

__global__ __launch_bounds__(512, 2) void gemm3p(
    const float* __restrict__ A0, const float* __restrict__ A1, int mtA0, long lda,
    const char* __restrict__ Bimg, int ktilesTot,
    float* __restrict__ C, long ldc, int MT, int NT, int KS, int swz)
{
  extern __shared__ char smemd[];
  const int tid = threadIdx.x;
  const int bid = blockIdx.x;

  int mt, nt, ks;
  if (swz) {
    int x = bid & 7, w = bid >> 3;
    nt = w & 3;
    int g = x + (w >> 2) * 8;
    mt = g & 15; ks = g >> 4;
  } else {
    nt = bid % NT; int q = bid / NT; mt = q % MT; ks = q / MT;
  }

  const int kt0 = (ktilesTot * ks) / KS;
  const int kt1 = (ktilesTot * (ks + 1)) / KS;

  const float* Ablk = (mt < mtA0) ? (A0 + (size_t)mt * 256 * lda)
                                  : (A1 + (size_t)(mt - mtA0) * 256 * lda);
  const char* Bt = Bimg + ((size_t)nt * ktilesTot + kt0) * 32768;

  const int wid = tid >> 6, lane = tid & 63;
  const int wr = wid >> 2, wc = wid & 3;
  const int l15 = lane & 15, lq = lane >> 4;

  const float* aSrc = Ablk + (size_t)(wid * 32 + (lane >> 3)) * lda
                      + (size_t)kt0 * 32 + 4 * (lane & 7);

  int awoff[4];
  {
    int kg = (lane & 7) >> 1, half = lane & 1;
#pragma unroll
    for (int i = 0; i < 4; ++i) {
      int m15 = (lane >> 3) + 8 * (i & 1);
      awoff[i] = (2 * wid + (i >> 1)) * 2048 + (((m15 ^ kg) + kg * 16) << 4) + half * 8;
    }
  }
  const int aroff = (((l15 ^ lq) + lq * 16) << 4);
  const int bbase = 32768 + (wc * 4) * 1024 + lane * 16;

  f32x4 acc[8][4];
#pragma unroll
  for (int m = 0; m < 8; ++m)
#pragma unroll
    for (int j = 0; j < 4; ++j)
#pragma unroll
      for (int e = 0; e < 4; ++e) acc[m][j][e] = 0.f;

  float4 aR[4];

#define ISSUE_A(KT)                                                            \
  {                                                                            \
    const float* p_ = aSrc + (size_t)((KT) - kt0) * 32;                        \
    _Pragma("unroll")                                                          \
    for (int i = 0; i < 4; ++i) aR[i] = *(const float4*)(p_ + (size_t)(8 * i) * lda); \
  }
#define ISSUE_B(DST, KT)                                                       \
  {                                                                            \
    const char* p_ = Bt + (size_t)((KT) - kt0) * 32768 + wid * 4096 + lane * 16; \
    _Pragma("unroll")                                                          \
    for (int i = 0; i < 4; ++i)                                                \
      gload16(p_ + i * 1024, (DST) + 32768 + wid * 4096 + i * 1024);           \
  }
#define WRITE_A(DST)                                                           \
  {                                                                            \
    _Pragma("unroll")                                                          \
    for (int i = 0; i < 4; ++i) {                                              \
      unsigned h0_, l0_, h1_, l1_;                                             \
      split2(aR[i].x, aR[i].y, h0_, l0_);                                      \
      split2(aR[i].z, aR[i].w, h1_, l1_);                                      \
      *(uint2*)((DST) + awoff[i])        = make_uint2(h0_, h1_);               \
      *(uint2*)((DST) + awoff[i] + 1024) = make_uint2(l0_, l1_);               \
    }                                                                          \
  }

  ISSUE_A(kt0);
  ISSUE_B(smemd, kt0);
  WRITE_A(smemd);
  asm volatile("s_waitcnt vmcnt(0)" ::: "memory");
  asm volatile("s_waitcnt lgkmcnt(0)" ::: "memory");
  __builtin_amdgcn_s_barrier();

  for (int kt = kt0; kt < kt1; ++kt) {
    char* bufc = smemd + (size_t)((kt - kt0) & 1) * 65536;
    char* bufn = smemd + (size_t)(((kt - kt0) & 1) ^ 1) * 65536;
    const bool nx = (kt + 1 < kt1);

    if (nx) { ISSUE_A(kt + 1); ISSUE_B(bufn, kt + 1); }

    bf16x8 bh[4], bl[4];
#pragma unroll
    for (int j = 0; j < 4; ++j) {
      bh[j] = *(const bf16x8*)(bufc + bbase + j * 1024);
      bl[j] = *(const bf16x8*)(bufc + bbase + j * 1024 + 16384);
    }

    __builtin_amdgcn_s_setprio(1);
#pragma unroll
    for (int m = 0; m < 4; ++m) {
      const char* ab = bufc + (wr * 8 + m) * 2048;
      bf16x8 ah = *(const bf16x8*)(ab + aroff);
      bf16x8 al = *(const bf16x8*)(ab + aroff + 1024);
#pragma unroll
      for (int j = 0; j < 4; ++j) {
        acc[m][j] = __builtin_amdgcn_mfma_f32_16x16x32_bf16(ah, bh[j], acc[m][j], 0, 0, 0);
        acc[m][j] = __builtin_amdgcn_mfma_f32_16x16x32_bf16(al, bh[j], acc[m][j], 0, 0, 0);
        acc[m][j] = __builtin_amdgcn_mfma_f32_16x16x32_bf16(ah, bl[j], acc[m][j], 0, 0, 0);
      }
    }
    __builtin_amdgcn_s_setprio(0);

    __builtin_amdgcn_sched_barrier(0);
    if (nx) WRITE_A(bufn);

    __builtin_amdgcn_s_setprio(1);
#pragma unroll
    for (int m = 4; m < 8; ++m) {
      const char* ab = bufc + (wr * 8 + m) * 2048;
      bf16x8 ah = *(const bf16x8*)(ab + aroff);
      bf16x8 al = *(const bf16x8*)(ab + aroff + 1024);
#pragma unroll
      for (int j = 0; j < 4; ++j) {
        acc[m][j] = __builtin_amdgcn_mfma_f32_16x16x32_bf16(ah, bh[j], acc[m][j], 0, 0, 0);
        acc[m][j] = __builtin_amdgcn_mfma_f32_16x16x32_bf16(al, bh[j], acc[m][j], 0, 0, 0);
        acc[m][j] = __builtin_amdgcn_mfma_f32_16x16x32_bf16(ah, bl[j], acc[m][j], 0, 0, 0);
      }
    }
    __builtin_amdgcn_s_setprio(0);

    asm volatile("s_waitcnt vmcnt(0)" ::: "memory");
    asm volatile("s_waitcnt lgkmcnt(0)" ::: "memory");
    __builtin_amdgcn_s_barrier();
  }
#undef ISSUE_A
#undef ISSUE_B
#undef WRITE_A

  float* Cb = C + (size_t)ks * (size_t)(MT * 256) * (size_t)ldc;
  const long rowbase = (long)mt * 256 + wr * 128 + lq * 4;
  const long colbase = (long)nt * 256 + wc * 64 + l15;
#pragma unroll
  for (int m = 0; m < 8; ++m)
#pragma unroll
    for (int j = 0; j < 4; ++j)
#pragma unroll
      for (int reg = 0; reg < 4; ++reg) {
        long row = rowbase + m * 16 + reg;
        long col = colbase + j * 16;
        Cb[(size_t)row * ldc + col] = acc[m][j][reg];
      }
}

// ---------------- epilogue: k-split sum, norm, Hamilton, row dot, sigmoid ----
__global__ void epilogue_kernel(const float* __restrict__ C1, const float* __restrict__ C2,
                                float* __restrict__ out, int KS)
{
  const int b = blockIdx.x;
  const int d = threadIdx.x;
  const size_t SZ = 4096ull * 1024ull;

  float Hq[4], Tq[4], Rq[4];
#pragma unroll
  for (int q = 0; q < 4; ++q) {
    float hv = 0.f, tv = 0.f;
    for (int ks = 0; ks < KS; ++ks) {
      hv += C1[ks * SZ + (size_t)b * 1024 + q * 256 + d];
      tv += C1[ks * SZ + (size_t)(b + 2048) * 1024 + q * 256 + d];
    }
    Hq[q] = hv; Tq[q] = tv;
    Rq[q] = C2[(size_t)b * 1024 + q * 256 + d];
  }
  float nn = Rq[0]*Rq[0] + Rq[1]*Rq[1] + Rq[2]*Rq[2] + Rq[3]*Rq[3];
  float Qr = Hq[0]*Rq[0] - Hq[1]*Rq[1] - Hq[2]*Rq[2] - Hq[3]*Rq[3];
  float Qi = Hq[0]*Rq[1] + Hq[1]*Rq[0] + Hq[2]*Rq[3] - Hq[3]*Rq[2];
  float Qj = Hq[0]*Rq[2] - Hq[1]*Rq[3] + Hq[2]*Rq[0] + Hq[3]*Rq[1];
  float Qk = Hq[0]*Rq[3] + Hq[1]*Rq[2] - Hq[2]*Rq[1] + Hq[3]*Rq[0];
  float ss = Qr*Tq[0] + Qi*Tq[1] + Qj*Tq[2] + Qk*Tq[3];

#pragma unroll
  for (int o = 32; o; o >>= 1) {
    ss += __shfl_xor(ss, o);
    nn += __shfl_xor(nn, o);
  }
  __shared__ float red[8];
  int lane = d & 63, w = d >> 6;
  if (lane == 0) { red[w] = ss; red[4 + w] = nn; }
  __syncthreads();
  if (d == 0) {
    float S = red[0] + red[1] + red[2] + red[3];
    float N = red[4] + red[5] + red[6] + red[7];
    float score = sqrtf(N) * S;
    out[b] = 1.f / (1.f + expf(-score));
  }
}

// ---------------- launch ----------------
extern "C" void kernel_launch(void* const* d_in, const int* in_sizes, int n_in,
                              void* d_out, int out_size, void* d_ws, size_t ws_size,
                              hipStream_t stream)
{
  const float* h = (const float*)d_in[0];
  const float* t = (const float*)d_in[1];
  const float* r = (const float*)d_in[2];
  const float* We[4] = {(const float*)d_in[3], (const float*)d_in[4],
                        (const float*)d_in[5], (const float*)d_in[6]};
  const float* Wr[4] = {(const float*)d_in[7], (const float*)d_in[8],
                        (const float*)d_in[9], (const float*)d_in[10]};
  float* out = (float*)d_out;
  char* ws = (char*)d_ws;

  // ---- image path ws layout (128-row tiles, 16KB each) ----
  const size_t offA  = 0;                               // A: 32 rt *625 *16KB = 327,680,000
  const size_t offB  = 327680000;                       // B: 8 rt *625 *16KB = 81,920,000
  const size_t offWr = offB + 81920000;                 // Wr: 8 rt *16 *16KB = 2,097,152
  const size_t offRi = offWr + 2097152;                 // r:  16 rt *16 *16KB = 4,194,304
  const size_t offC1 = offRi + 4194304;
  const size_t C1sz  = 4096ull * 1024ull * 4ull;        // 16,777,216 per ks
  const size_t offC2 = offC1 + 2 * C1sz;                // KS=2
  const size_t needImg = offC2 + 8388608;               // ~458 MB

  if (ws_size >= needImg) {
    float* C1 = (float*)(ws + offC1);
    float* C2 = (float*)(ws + offC2);

    // A images: rows 0..2047 = h, 2048..4095 = t  (64 x 64-row blocks)
    convert_img128<<<dim3(625, 64), 256, 0, stream>>>(h, t, 2048, 20000, ws + offA, 625);
    for (int q = 0; q < 4; ++q) {
      convert_img128<<<dim3(625, 4), 256, 0, stream>>>(
          We[q], We[q], 2048, 20000, ws + offB + (size_t)q * 2 * 625 * 16384, 625);
      convert_img128<<<dim3(16, 4), 256, 0, stream>>>(
          Wr[q], Wr[q], 2048, 500, ws + offWr + (size_t)q * 2 * 16 * 16384, 16);
    }
    convert_img128<<<dim3(16, 32), 256, 0, stream>>>(r, r, 2048, 500, ws + offRi, 16);

    // main: M=4096 (32 mt), N=1024 (8 nt), K=20000 (625 kt), KS=2 -> 512 blocks (2/CU)
    gemm_t128<<<dim3(512), 256, 0, stream>>>(
        ws + offA, ws + offB, 625, C1, 32, 8, 2, 1);
    // r: M=2048 (16 mt), N=1024 (8 nt), K=512 (16 kt), KS=1 -> 128 blocks
    gemm_t128<<<dim3(128), 256, 0, stream>>>(
        ws + offRi, ws + offWr, 16, C2, 16, 8, 1, 0);

    epilogue_kernel<<<dim3(2048), 256, 0, stream>>>(C1, C2, out, 2);
    return;
  }

  // ---- fallback: R3 path ----
  const size_t fB  = 0;
  const size_t fWr = 81920000;
  const size_t fR  = fWr + 2097152;
  const size_t fC1 = fR + 4194304;
  const int KS = (ws_size >= fC1 + 4 * C1sz + 8388608ull) ? 4 : 2;
  const size_t fC2 = fC1 + (size_t)KS * C1sz;

  float* rpad = (float*)(ws + fR);
  float* C1   = (float*)(ws + fC1);
  float* C2   = (float*)(ws + fC2);

  for (int q = 0; q < 4; ++q) {
    convert_b16<<<dim3(625), 256, 0, stream>>>(We[q], 20000, ws + fB + (size_t)q * 625 * 32768);
    convert_b16<<<dim3(16), 256, 0, stream>>>(Wr[q], 500, ws + fWr + (size_t)q * 16 * 32768);
  }
  pad_r<<<dim3(1, 2048), 128, 0, stream>>>(r, rpad);

  gemm3p<<<dim3(16 * 4 * KS), 512, 131072, stream>>>(
      h, t, 8, 20000L, (const char*)(ws + fB), 625,
      C1, 1024L, 16, 4, KS, KS == 4 ? 1 : 0);
  gemm3p<<<dim3(32), 512, 131072, stream>>>(
      rpad, rpad, 8, 512L, (const char*)(ws + fWr), 16,
      C2, 1024L, 8, 4, 1, 0);

  epilogue_kernel<<<dim3(2048), 256, 0, stream>>>(C1, C2, out, KS);
}